// Round 19
// baseline (56.105 us; speedup 1.0000x reference)
//
#include <hip/hip_runtime.h>
#include <cstdint>
#include <cstddef>

#define BB 16
#define AA 8400
#define CC 80
#define MM 32
#define TOPK 13
#define NW 8                 // waves (chunks) per row-block
#define CANCH 1056           // anchors per wave-chunk (8*1056 = 8448 >= AA)

// Shared CIoU (clipped) so every use site has the identical formula.
__device__ __forceinline__ float ciou_clip(
    float gx1, float gy1, float gx2, float gy2, float at1,
    float4 pb, float w2, float h2, float at2)
{
  const float w1 = gx2 - gx1, h1 = gy2 - gy1 + 1e-7f;
  const float iw = fmaxf(fminf(gx2, pb.z) - fmaxf(gx1, pb.x), 0.f);
  const float ih = fmaxf(fminf(gy2, pb.w) - fmaxf(gy1, pb.y), 0.f);
  const float inter = iw * ih;
  const float uni = w1*h1 + w2*h2 - inter + 1e-7f;
  const float iou = inter / uni;
  const float cw = fmaxf(gx2, pb.z) - fminf(gx1, pb.x);
  const float ch = fmaxf(gy2, pb.w) - fminf(gy1, pb.y);
  const float c2 = cw*cw + ch*ch + 1e-7f;
  const float rx = pb.x + pb.z - gx1 - gx2;
  const float ry = pb.y + pb.w - gy1 - gy2;
  const float rho2 = (rx*rx + ry*ry) * 0.25f;
  const float dv = at2 - at1;
  const float v = 0.4052847345693511f * dv * dv;
  const float alpha = v / (v - iou + (1.f + 1e-7f));
  return fmaxf(iou - (rho2 / c2 + v * alpha), 0.f);
}

// (val desc, idx asc) as one monotone u64 key; val >= 0 so float bits are
// order-preserving. Sentinel/empty = 0 (loses to every real entry; decodes
// to anchor -1 — ALL decode sites must use unsigned bounds checks).
__device__ __forceinline__ unsigned long long pack_key(float val, int a) {
  return ((unsigned long long)__float_as_uint(val) << 32)
       | (unsigned long long)(0xFFFFFFFFu - (unsigned)a);
}
__device__ __forceinline__ int key_anchor(unsigned long long k) {
  return (int)(0xFFFFFFFFu - (unsigned)(k & 0xFFFFFFFFull));
}

// ---------------------------------------------------------------------------
// K1: per-(b,m) block (8 waves, 512 thr): mind-test scan -> LDS queue ->
// dense CIoU eval -> per-lane top-13 u64 keys -> per-wave butterfly extract
// -> wave-0 merge of 8x13 -> topkeys[b][m][13]. Masked rows: sentinel keys.
// (Verbatim from the R16 absmax=0 version — best-measured k_topk variant.)
// ---------------------------------------------------------------------------
__global__ __launch_bounds__(512) void k_topk(
    const float* __restrict__ pred_cls, const float* __restrict__ pred_bbox,
    const float* __restrict__ anchors, const int* __restrict__ gt_cls,
    const float* __restrict__ gt_bbox, const float* __restrict__ mask_gt,
    unsigned long long* __restrict__ topkeys)
{
  const int m = blockIdx.x, b = blockIdx.y;
  const int tid = threadIdx.x;
  const int wave = tid >> 6, lane = tid & 63;

  unsigned long long* tk = topkeys + (size_t)(b*MM + m)*TOPK;
  if (mask_gt[b*MM + m] <= 0.f) {        // masked gt: sentinel row
    if (tid < TOPK) tk[tid] = 0ull;
    return;
  }

  __shared__ unsigned short q[NW][CANCH];
  __shared__ unsigned long long s_top[NW][TOPK];

  const float4 gb = reinterpret_cast<const float4*>(gt_bbox)[b*MM + m];
  const float at1 = atanf((gb.z - gb.x) / (gb.w - gb.y + 1e-7f));
  const int lbl = gt_cls[b*MM + m];
  const float*  clsbase = pred_cls + (size_t)b*AA*CC;
  const float4* pbase   = reinterpret_cast<const float4*>(pred_bbox) + (size_t)b*AA;
  const float2* axy     = reinterpret_cast<const float2*>(anchors);

  unsigned long long k13[TOPK];
  #pragma unroll
  for (int i = 0; i < TOPK; ++i) k13[i] = 0ull;

  // wave-0 seed: full eval of anchor a = lane (always a candidate;
  // provides the exact zero-tie fill when a row has <13 positives)
  if (wave == 0) {
    const int a = lane;
    const float2 xy = axy[a];
    const float mind = fminf(fminf(xy.x - gb.x, xy.y - gb.y),
                             fminf(gb.z - xy.x, gb.w - xy.y));
    float val = 0.f;
    if (mind > 1e-9f) {
      const float4 pb = pbase[a];
      const float w2 = pb.z - pb.x, h2 = pb.w - pb.y + 1e-7f;
      const float at2 = atanf(w2 / h2);
      const float ov = ciou_clip(gb.x, gb.y, gb.z, gb.w, at1, pb, w2, h2, at2);
      const float o2 = ov * ov;
      val = clsbase[(size_t)a*CC + lbl] * (o2 * o2 * o2);
    }
    k13[0] = pack_key(val, a);
  }

  // mind-test scan -> queue (ascending anchor order)
  const int abase = wave * CANCH;
  int qc = 0;
  for (int s = 0; s < 17; ++s) {
    const int la = s*64 + lane;
    const int a  = abase + la;
    bool pass = false;
    if (la < CANCH && a < AA && !(wave == 0 && a < 64)) {
      const float2 xy = axy[a];
      const float mind = fminf(fminf(xy.x - gb.x, xy.y - gb.y),
                               fminf(gb.z - xy.x, gb.w - xy.y));
      pass = mind > 1e-9f;
    }
    const unsigned long long bal = __ballot(pass);
    if (pass) {
      const int pos = qc + (int)__popcll(bal & ((1ull << lane) - 1ull));
      q[wave][pos] = (unsigned short)la;
    }
    qc += (int)__popcll(bal);
  }

  // dense eval of queue (per-lane stream ascending in a; key compare exact)
  for (int k = lane; k < qc; k += 64) {
    const int a = abase + (int)q[wave][k];
    const float4 pb = pbase[a];
    const float w2 = pb.z - pb.x, h2 = pb.w - pb.y + 1e-7f;
    const float at2 = atanf(w2 / h2);
    const float ov = ciou_clip(gb.x, gb.y, gb.z, gb.w, at1, pb, w2, h2, at2);
    const float o2 = ov * ov;
    const float val = clsbase[(size_t)a*CC + lbl] * (o2 * o2 * o2);
    const unsigned long long key = pack_key(val, a);
    if (key > k13[TOPK-1]) {
      #pragma unroll
      for (int i = TOPK-1; i >= 1; --i)       // static-index shift network
        if (key > k13[i]) k13[i] = (key > k13[i-1]) ? k13[i-1] : key;
      if (key > k13[0]) k13[0] = key;
    }
  }

  // per-wave 13-round extraction (u64 butterfly max) -> LDS
  for (int r = 0; r < TOPK; ++r) {
    unsigned long long bk = k13[0];
    #pragma unroll
    for (int off = 32; off; off >>= 1) {
      const unsigned long long o = __shfl_xor(bk, off);
      if (o > bk) bk = o;
    }
    if (k13[0] == bk) {                       // unique for real keys;
      #pragma unroll                          // sentinel multi-pop harmless
      for (int i = 0; i < TOPK-1; ++i) k13[i] = k13[i+1];
      k13[TOPK-1] = 0ull;
    }
    if (lane == 0) s_top[wave][r] = bk;
  }
  __syncthreads();
  if (wave != 0) return;

  // wave-0 merge of 8x13 = 104 keys (2 static slots/lane) -> topkeys row
  unsigned long long v0 = 0ull, v1 = 0ull;
  {
    const int e0 = lane, e1 = lane + 64;
    v0 = s_top[e0/TOPK][e0%TOPK];
    if (e1 < NW*TOPK) v1 = s_top[e1/TOPK][e1%TOPK];
  }
  for (int r = 0; r < TOPK; ++r) {
    const bool s1 = v1 > v0;
    unsigned long long bk = s1 ? v1 : v0;
    const unsigned long long my = bk;
    #pragma unroll
    for (int off = 32; off; off >>= 1) {
      const unsigned long long o = __shfl_xor(bk, off);
      if (o > bk) bk = o;
    }
    if (lane == 0) tk[r] = bk;
    if (my == bk && bk != 0ull) {             // unique winner pops its slot
      if (s1) v1 = 0ull; else v0 = 0ull;
    }
  }
}

// ---------------------------------------------------------------------------
// K2: ONE block per batch (16 blocks, 512 thr): claim bitmap from 416 keys
// (in-gts gate, unsigned sentinel guards) -> ballot-compacted list -> ONE
// dense resolve round -> writes asg[u8] (255 default), av[f32] (claimed
// only; unread otherwise), and final pos_align/pos_ovl. Tiny kernel — the
// per-batch serial phases run ONCE (R16 ran them 17x per batch and its
// 272-block grid had a 2x tail on 16 CUs: the measured 21us).
// ---------------------------------------------------------------------------
__global__ __launch_bounds__(512) void k_pos(
    const float* __restrict__ pred_cls, const float* __restrict__ pred_bbox,
    const float* __restrict__ anchors, const int* __restrict__ gt_cls,
    const float* __restrict__ gt_bbox, const float* __restrict__ mask_gt,
    const unsigned long long* __restrict__ topkeys,
    unsigned char* __restrict__ asg_arr, float* __restrict__ av_arr,
    float* __restrict__ pos_align, float* __restrict__ pos_ovl)
{
  const int b = blockIdx.x;
  const int tid = threadIdx.x;
  const int lane = tid & 63;

  __shared__ unsigned int s_claim[AA];      // 33600 B
  __shared__ unsigned short s_list[MM*TOPK];
  __shared__ int s_ncl;
  __shared__ unsigned int s_pal[MM], s_pov[MM];
  __shared__ float4 s_gb[MM];
  __shared__ float s_at[MM], s_mgt[MM];
  __shared__ int s_lbl[MM];

  const float2* axy   = reinterpret_cast<const float2*>(anchors);
  const float4* pbase = reinterpret_cast<const float4*>(pred_bbox) + (size_t)b*AA;

  if (tid < MM) {
    const float4 g = reinterpret_cast<const float4*>(gt_bbox)[b*MM + tid];
    s_gb[tid] = g;
    s_at[tid] = atanf((g.z - g.x) / (g.w - g.y + 1e-7f));
    s_lbl[tid] = gt_cls[b*MM + tid];
    s_mgt[tid] = mask_gt[b*MM + tid];
    s_pal[tid] = 0u; s_pov[tid] = 0u;
  }
  if (tid == 0) s_ncl = 0;
  for (int a = tid; a < AA; a += 512) {
    s_claim[a] = 0u;
    asg_arr[(size_t)b*AA + a] = 255;          // default: unassigned
  }
  __syncthreads();

  // claim phase: 416 keys -> bitmap (in-gts gate here)
  if (tid < MM*TOPK) {
    const int m = tid / TOPK;
    const unsigned long long key = topkeys[(size_t)(b*MM + m)*TOPK + tid%TOPK];
    const int a = key_anchor(key);
    if ((unsigned)a < (unsigned)AA) {         // rejects sentinel (-1)
      const float2 xy = axy[a];
      const float4 g = s_gb[m];
      const float mind = fminf(fminf(xy.x - g.x, xy.y - g.y),
                               fminf(g.z - xy.x, g.w - xy.y));
      if (mind > 1e-9f) atomicOr(&s_claim[a], 1u << m);
    }
  }
  __syncthreads();

  // compact phase: claimed anchors -> s_list (cheap: no float work)
  for (int a = tid; a < AA; a += 512) {
    const bool c = s_claim[a] != 0u;
    const unsigned long long bal = __ballot(c);
    int base = 0;
    if (lane == 0 && bal) base = atomicAdd(&s_ncl, (int)__popcll(bal));
    base = __shfl(base, 0);
    if (c) s_list[base + (int)__popcll(bal & ((1ull << lane) - 1ull))]
             = (unsigned short)a;
  }
  __syncthreads();
  const int ncl = s_ncl;                      // <= 416

  // dense resolve: ONE round, all lanes on real work
  for (int k = tid; k < ncl; k += 512) {
    const int a = (int)s_list[k];
    const unsigned cb = s_claim[a];
    const float4 pb = pbase[a];
    const float2 xy = axy[a];
    const float w2 = pb.z - pb.x, h2 = pb.w - pb.y + 1e-7f;
    const float at2 = atanf(w2 / h2);
    int asg; float bestov;
    if (__popc(cb) == 1) {
      asg = __ffs(cb) - 1;   // claimed => in-gts && mask_gt>0 already hold
      const float4 g = s_gb[asg];
      bestov = ciou_clip(g.x, g.y, g.z, g.w, s_at[asg], pb, w2, h2, at2);
    } else {
      // is_max: first argmax over ALL m of masked overlaps
      float best = -1.f; int bm = 0;
      for (int m = 0; m < MM; ++m) {
        float ov = 0.f;
        const float4 g = s_gb[m];
        const float mind = fminf(fminf(xy.x - g.x, xy.y - g.y),
                                 fminf(g.z - xy.x, g.w - xy.y));
        if (mind > 1e-9f && s_mgt[m] > 0.f)
          ov = ciou_clip(g.x, g.y, g.z, g.w, s_at[m], pb, w2, h2, at2);
        if (ov > best) { best = ov; bm = m; }   // strict > => first max
      }
      asg = bm; bestov = best;
    }
    const float o2 = bestov * bestov;
    const float av = pred_cls[(size_t)(b*AA + a)*CC + s_lbl[asg]] * (o2*o2*o2);
    atomicMax(&s_pal[asg], __float_as_uint(av));      // >=0 floats
    atomicMax(&s_pov[asg], __float_as_uint(bestov));
    asg_arr[(size_t)b*AA + a] = (unsigned char)asg;   // barrier-ordered after init
    av_arr[(size_t)b*AA + a]  = av;
  }
  __syncthreads();

  if (tid < MM) {
    pos_align[b*MM + tid] = __uint_as_float(s_pal[tid]);
    pos_ovl[b*MM + tid]   = __uint_as_float(s_pov[tid]);
  }
}

// ---------------------------------------------------------------------------
// K3: output streaming — 1056 blocks (b, 128-anchor window) x 256 thr
// (~4 blocks/CU: tail-free, write-BW-bound). Reads asg/av/pos, writes
// out_cls (float4-coalesced), out_bbox, out_fg.
// ---------------------------------------------------------------------------
__global__ __launch_bounds__(256) void k_out(
    const unsigned char* __restrict__ asg_arr, const float* __restrict__ av_arr,
    const float* __restrict__ pos_align, const float* __restrict__ pos_ovl,
    const int* __restrict__ gt_cls, const float* __restrict__ gt_bbox,
    float* __restrict__ out_cls, float* __restrict__ out_bbox,
    float* __restrict__ out_fg)
{
  const int b = blockIdx.x / 66, win = blockIdx.x % 66;
  const int tid = threadIdx.x;
  const int a0 = win * 128;
  const int na = (a0 + 128 <= AA) ? 128 : (AA - a0);   // a0 <= 8320 always

  __shared__ float4 s_gb[MM];
  __shared__ float s_pal[MM], s_pov[MM];
  __shared__ int s_lbl[MM];
  __shared__ unsigned char s_asg[128];
  __shared__ float s_av[128];

  if (tid < MM) {
    s_gb[tid]  = reinterpret_cast<const float4*>(gt_bbox)[b*MM + tid];
    s_lbl[tid] = gt_cls[b*MM + tid];
    s_pal[tid] = pos_align[b*MM + tid];
    s_pov[tid] = pos_ovl[b*MM + tid];
  }
  if (tid < 128 && tid < na) {
    const size_t ba = (size_t)b*AA + a0 + tid;
    const unsigned char g = asg_arr[ba];
    s_asg[tid] = g;
    s_av[tid]  = (g != 255) ? av_arr[ba] : 0.f;
  }
  __syncthreads();

  // out_cls: na anchors x 20 float4, consecutive threads -> consecutive 16B
  float4* ocw = reinterpret_cast<float4*>(out_cls) + ((size_t)(b*AA + a0)) * (CC/4);
  for (int j = tid; j < na*(CC/4); j += 256) {
    const int ai = j / (CC/4);
    const int q4 = j % (CC/4);
    const int asg = s_asg[ai];
    float4 o = make_float4(0.f, 0.f, 0.f, 0.f);
    if (asg != 255) {
      const float norm = s_av[ai] * s_pov[asg] / (s_pal[asg] + 1e-9f);
      const int lbl = s_lbl[asg];
      const int c0 = q4 * 4;
      if (lbl == c0    ) o.x = norm;
      if (lbl == c0 + 1) o.y = norm;
      if (lbl == c0 + 2) o.z = norm;
      if (lbl == c0 + 3) o.w = norm;
    }
    ocw[j] = o;
  }
  if (tid < na) {
    const int a = a0 + tid;
    const int asg = s_asg[tid];
    const int tgt = (asg != 255) ? asg : 0;   // argmax of all-zero column = 0
    reinterpret_cast<float4*>(out_bbox)[b*AA + a] = s_gb[tgt];
    out_fg[b*AA + a] = (asg != 255) ? 1.f : 0.f;
  }
}

// ---------------------------------------------------------------------------
extern "C" void kernel_launch(void* const* d_in, const int* in_sizes, int n_in,
                              void* d_out, int out_size, void* d_ws, size_t ws_size,
                              hipStream_t stream)
{
  const float* pred_cls  = (const float*)d_in[0];
  const float* pred_bbox = (const float*)d_in[1];
  const float* anchors   = (const float*)d_in[2];
  const int*   gt_cls    = (const int*)  d_in[3];
  const float* gt_bbox   = (const float*)d_in[4];
  const float* mask_gt   = (const float*)d_in[5];

  // ws layout:
  //   topkeys    : B*M*13 u64     @ 0        (53248 B)
  //   pos_align  : B*M f32        @ 53248    (2048 B)
  //   pos_ovl    : B*M f32        @ 55296    (2048 B)
  //   asg        : B*A u8         @ 57344    (134400 B)
  //   av         : B*A f32        @ 192000   (537600 B)   (16B-aligned)
  // total 729600 B
  char* ws = (char*)d_ws;
  unsigned long long* topkeys = (unsigned long long*)(ws);
  float* pos_align = (float*)(ws + 53248);
  float* pos_ovl   = (float*)(ws + 55296);
  unsigned char* asg_arr = (unsigned char*)(ws + 57344);
  float* av_arr    = (float*)(ws + 192000);

  float* out_cls  = (float*)d_out;
  float* out_bbox = out_cls + (size_t)BB*AA*CC;
  float* out_fg   = out_bbox + (size_t)BB*AA*4;

  k_topk<<<dim3(MM, BB), 512, 0, stream>>>(
      pred_cls, pred_bbox, anchors, gt_cls, gt_bbox, mask_gt, topkeys);
  k_pos<<<dim3(BB), 512, 0, stream>>>(
      pred_cls, pred_bbox, anchors, gt_cls, gt_bbox, mask_gt, topkeys,
      asg_arr, av_arr, pos_align, pos_ovl);
  k_out<<<dim3(BB*66), 256, 0, stream>>>(
      asg_arr, av_arr, pos_align, pos_ovl, gt_cls, gt_bbox,
      out_cls, out_bbox, out_fg);
}

// Round 20
// 52.360 us; speedup vs baseline: 1.0715x; 1.0715x over previous
//
#include <hip/hip_runtime.h>
#include <cstdint>
#include <cstddef>

#define BB 16
#define AA 8400
#define CC 80
#define MM 32
#define TOPK 13
#define NW 8                 // waves (chunks) per row-block
#define CANCH 1056           // anchors per wave-chunk (8*1056 = 8448 >= AA)

// Shared CIoU (clipped) so every use site has the identical formula.
__device__ __forceinline__ float ciou_clip(
    float gx1, float gy1, float gx2, float gy2, float at1,
    float4 pb, float w2, float h2, float at2)
{
  const float w1 = gx2 - gx1, h1 = gy2 - gy1 + 1e-7f;
  const float iw = fmaxf(fminf(gx2, pb.z) - fmaxf(gx1, pb.x), 0.f);
  const float ih = fmaxf(fminf(gy2, pb.w) - fmaxf(gy1, pb.y), 0.f);
  const float inter = iw * ih;
  const float uni = w1*h1 + w2*h2 - inter + 1e-7f;
  const float iou = inter / uni;
  const float cw = fmaxf(gx2, pb.z) - fminf(gx1, pb.x);
  const float ch = fmaxf(gy2, pb.w) - fminf(gy1, pb.y);
  const float c2 = cw*cw + ch*ch + 1e-7f;
  const float rx = pb.x + pb.z - gx1 - gx2;
  const float ry = pb.y + pb.w - gy1 - gy2;
  const float rho2 = (rx*rx + ry*ry) * 0.25f;
  const float dv = at2 - at1;
  const float v = 0.4052847345693511f * dv * dv;
  const float alpha = v / (v - iou + (1.f + 1e-7f));
  return fmaxf(iou - (rho2 / c2 + v * alpha), 0.f);
}

// (val desc, idx asc) as one monotone u64 key; val >= 0 so float bits are
// order-preserving. Sentinel/empty = 0 (loses to every real entry; decodes
// to anchor -1 — ALL decode sites must use unsigned bounds checks).
__device__ __forceinline__ unsigned long long pack_key(float val, int a) {
  return ((unsigned long long)__float_as_uint(val) << 32)
       | (unsigned long long)(0xFFFFFFFFu - (unsigned)a);
}
__device__ __forceinline__ int key_anchor(unsigned long long k) {
  return (int)(0xFFFFFFFFu - (unsigned)(k & 0xFFFFFFFFull));
}

// ---------------------------------------------------------------------------
// K1: per-(b,m) block (8 waves, 512 thr): mind-test scan -> LDS queue ->
// dense CIoU eval -> per-lane top-13 u64 keys -> per-wave butterfly extract
// -> wave-0 merge of 8x13 -> topkeys[b][m][13]. Masked rows: sentinel keys.
// (Verbatim from R14/R16 absmax=0 lineage — best-measured k_topk variant.)
// ---------------------------------------------------------------------------
__global__ __launch_bounds__(512) void k_topk(
    const float* __restrict__ pred_cls, const float* __restrict__ pred_bbox,
    const float* __restrict__ anchors, const int* __restrict__ gt_cls,
    const float* __restrict__ gt_bbox, const float* __restrict__ mask_gt,
    unsigned long long* __restrict__ topkeys)
{
  const int m = blockIdx.x, b = blockIdx.y;
  const int tid = threadIdx.x;
  const int wave = tid >> 6, lane = tid & 63;

  unsigned long long* tk = topkeys + (size_t)(b*MM + m)*TOPK;
  if (mask_gt[b*MM + m] <= 0.f) {        // masked gt: sentinel row
    if (tid < TOPK) tk[tid] = 0ull;
    return;
  }

  __shared__ unsigned short q[NW][CANCH];
  __shared__ unsigned long long s_top[NW][TOPK];

  const float4 gb = reinterpret_cast<const float4*>(gt_bbox)[b*MM + m];
  const float at1 = atanf((gb.z - gb.x) / (gb.w - gb.y + 1e-7f));
  const int lbl = gt_cls[b*MM + m];
  const float*  clsbase = pred_cls + (size_t)b*AA*CC;
  const float4* pbase   = reinterpret_cast<const float4*>(pred_bbox) + (size_t)b*AA;
  const float2* axy     = reinterpret_cast<const float2*>(anchors);

  unsigned long long k13[TOPK];
  #pragma unroll
  for (int i = 0; i < TOPK; ++i) k13[i] = 0ull;

  // wave-0 seed: full eval of anchor a = lane (always a candidate;
  // provides the exact zero-tie fill when a row has <13 positives)
  if (wave == 0) {
    const int a = lane;
    const float2 xy = axy[a];
    const float mind = fminf(fminf(xy.x - gb.x, xy.y - gb.y),
                             fminf(gb.z - xy.x, gb.w - xy.y));
    float val = 0.f;
    if (mind > 1e-9f) {
      const float4 pb = pbase[a];
      const float w2 = pb.z - pb.x, h2 = pb.w - pb.y + 1e-7f;
      const float at2 = atanf(w2 / h2);
      const float ov = ciou_clip(gb.x, gb.y, gb.z, gb.w, at1, pb, w2, h2, at2);
      const float o2 = ov * ov;
      val = clsbase[(size_t)a*CC + lbl] * (o2 * o2 * o2);
    }
    k13[0] = pack_key(val, a);
  }

  // mind-test scan -> queue (ascending anchor order)
  const int abase = wave * CANCH;
  int qc = 0;
  for (int s = 0; s < 17; ++s) {
    const int la = s*64 + lane;
    const int a  = abase + la;
    bool pass = false;
    if (la < CANCH && a < AA && !(wave == 0 && a < 64)) {
      const float2 xy = axy[a];
      const float mind = fminf(fminf(xy.x - gb.x, xy.y - gb.y),
                               fminf(gb.z - xy.x, gb.w - xy.y));
      pass = mind > 1e-9f;
    }
    const unsigned long long bal = __ballot(pass);
    if (pass) {
      const int pos = qc + (int)__popcll(bal & ((1ull << lane) - 1ull));
      q[wave][pos] = (unsigned short)la;
    }
    qc += (int)__popcll(bal);
  }

  // dense eval of queue (per-lane stream ascending in a; key compare exact)
  for (int k = lane; k < qc; k += 64) {
    const int a = abase + (int)q[wave][k];
    const float4 pb = pbase[a];
    const float w2 = pb.z - pb.x, h2 = pb.w - pb.y + 1e-7f;
    const float at2 = atanf(w2 / h2);
    const float ov = ciou_clip(gb.x, gb.y, gb.z, gb.w, at1, pb, w2, h2, at2);
    const float o2 = ov * ov;
    const float val = clsbase[(size_t)a*CC + lbl] * (o2 * o2 * o2);
    const unsigned long long key = pack_key(val, a);
    if (key > k13[TOPK-1]) {
      #pragma unroll
      for (int i = TOPK-1; i >= 1; --i)       // static-index shift network
        if (key > k13[i]) k13[i] = (key > k13[i-1]) ? k13[i-1] : key;
      if (key > k13[0]) k13[0] = key;
    }
  }

  // per-wave 13-round extraction (u64 butterfly max) -> LDS
  for (int r = 0; r < TOPK; ++r) {
    unsigned long long bk = k13[0];
    #pragma unroll
    for (int off = 32; off; off >>= 1) {
      const unsigned long long o = __shfl_xor(bk, off);
      if (o > bk) bk = o;
    }
    if (k13[0] == bk) {                       // unique for real keys;
      #pragma unroll                          // sentinel multi-pop harmless
      for (int i = 0; i < TOPK-1; ++i) k13[i] = k13[i+1];
      k13[TOPK-1] = 0ull;
    }
    if (lane == 0) s_top[wave][r] = bk;
  }
  __syncthreads();
  if (wave != 0) return;

  // wave-0 merge of 8x13 = 104 keys (2 static slots/lane) -> topkeys row
  unsigned long long v0 = 0ull, v1 = 0ull;
  {
    const int e0 = lane, e1 = lane + 64;
    v0 = s_top[e0/TOPK][e0%TOPK];
    if (e1 < NW*TOPK) v1 = s_top[e1/TOPK][e1%TOPK];
  }
  for (int r = 0; r < TOPK; ++r) {
    const bool s1 = v1 > v0;
    unsigned long long bk = s1 ? v1 : v0;
    const unsigned long long my = bk;
    #pragma unroll
    for (int off = 32; off; off >>= 1) {
      const unsigned long long o = __shfl_xor(bk, off);
      if (o > bk) bk = o;
    }
    if (lane == 0) tk[r] = bk;
    if (my == bk && bk != 0ull) {             // unique winner pops its slot
      if (s1) v1 = 0ull; else v0 = 0ull;
    }
  }
}

// ---------------------------------------------------------------------------
// K2: 272 blocks (b, 512-anchor window), 512 thr. R16's proven claim ->
// compact -> ONE dense resolve round (pos bitwise-identical across the
// batch's 17 blocks), but the write phase is now SPARSE: d_out was
// pre-zeroed by hipMemsetAsync, so only out_bbox is written densely
// (unassigned anchors need gt_bbox[b][0], not zero); fg=1 and
// cls[label]=norm are written only for claimed anchors (<=416/batch).
// Our kernels' dense-write traffic drops 46.6 MB -> 2.7 MB.
// ---------------------------------------------------------------------------
__global__ __launch_bounds__(512) void k_assign(
    const float* __restrict__ pred_cls, const float* __restrict__ pred_bbox,
    const float* __restrict__ anchors, const int* __restrict__ gt_cls,
    const float* __restrict__ gt_bbox, const float* __restrict__ mask_gt,
    const unsigned long long* __restrict__ topkeys,
    float* __restrict__ out_cls, float* __restrict__ out_bbox,
    float* __restrict__ out_fg)
{
  const int b = blockIdx.x / 17, ch = blockIdx.x % 17;
  const int tid = threadIdx.x;
  const int lane = tid & 63;
  const int w0 = ch * 512;                  // window [w0, w0+nw)
  const int nw = (w0 + 512 <= AA) ? 512 : (AA - w0);

  __shared__ unsigned int s_claim[AA];      // 33600 B, full-batch bitmap
  __shared__ unsigned short s_list[MM*TOPK];// compacted claimed anchors
  __shared__ int s_ncl;
  __shared__ unsigned char s_asg[512];      // window assignment (255 = none)
  __shared__ float s_av[512];               // window align value
  __shared__ unsigned int s_pal[MM], s_pov[MM];
  __shared__ float4 s_gb[MM];
  __shared__ float s_at[MM], s_mgt[MM];
  __shared__ int s_lbl[MM];

  const float2* axy   = reinterpret_cast<const float2*>(anchors);
  const float4* pbase = reinterpret_cast<const float4*>(pred_bbox) + (size_t)b*AA;

  if (tid < MM) {
    const float4 g = reinterpret_cast<const float4*>(gt_bbox)[b*MM + tid];
    s_gb[tid] = g;
    s_at[tid] = atanf((g.z - g.x) / (g.w - g.y + 1e-7f));
    s_lbl[tid] = gt_cls[b*MM + tid];
    s_mgt[tid] = mask_gt[b*MM + tid];
    s_pal[tid] = 0u; s_pov[tid] = 0u;
  }
  if (tid == 0) s_ncl = 0;
  s_asg[tid] = 255;
  for (int k = tid; k < AA; k += 512) s_claim[k] = 0u;
  __syncthreads();

  // claim phase: 416 keys -> full-batch bitmap (in-gts gate here)
  if (tid < MM*TOPK) {
    const int m = tid / TOPK;
    const unsigned long long key = topkeys[(size_t)(b*MM + m)*TOPK + tid%TOPK];
    const int a = key_anchor(key);
    if ((unsigned)a < (unsigned)AA) {       // rejects sentinel (-1)
      const float2 xy = axy[a];
      const float4 g = s_gb[m];
      const float mind = fminf(fminf(xy.x - g.x, xy.y - g.y),
                               fminf(g.z - xy.x, g.w - xy.y));
      if (mind > 1e-9f) atomicOr(&s_claim[a], 1u << m);
    }
  }
  __syncthreads();

  // compact phase: claimed anchors -> s_list (cheap: no float work)
  for (int a = tid; a < AA; a += 512) {
    const bool c = s_claim[a] != 0u;
    const unsigned long long bal = __ballot(c);
    int base = 0;
    if (lane == 0 && bal) base = atomicAdd(&s_ncl, (int)__popcll(bal));
    base = __shfl(base, 0);
    if (c) s_list[base + (int)__popcll(bal & ((1ull << lane) - 1ull))]
             = (unsigned short)a;
  }
  __syncthreads();
  const int ncl = s_ncl;                    // <= 416

  // dense resolve: ONE round, all lanes on real work
  for (int k = tid; k < ncl; k += 512) {
    const int a = (int)s_list[k];
    const unsigned cb = s_claim[a];
    const float4 pb = pbase[a];
    const float2 xy = axy[a];
    const float w2 = pb.z - pb.x, h2 = pb.w - pb.y + 1e-7f;
    const float at2 = atanf(w2 / h2);
    int asg; float bestov;
    if (__popc(cb) == 1) {
      asg = __ffs(cb) - 1;   // claimed => in-gts && mask_gt>0 already hold
      const float4 g = s_gb[asg];
      bestov = ciou_clip(g.x, g.y, g.z, g.w, s_at[asg], pb, w2, h2, at2);
    } else {
      // is_max: first argmax over ALL m of masked overlaps
      float best = -1.f; int bm = 0;
      for (int m = 0; m < MM; ++m) {
        float ov = 0.f;
        const float4 g = s_gb[m];
        const float mind = fminf(fminf(xy.x - g.x, xy.y - g.y),
                                 fminf(g.z - xy.x, g.w - xy.y));
        if (mind > 1e-9f && s_mgt[m] > 0.f)
          ov = ciou_clip(g.x, g.y, g.z, g.w, s_at[m], pb, w2, h2, at2);
        if (ov > best) { best = ov; bm = m; }   // strict > => first max
      }
      asg = bm; bestov = best;
    }
    const float o2 = bestov * bestov;
    const float av = pred_cls[(size_t)(b*AA + a)*CC + s_lbl[asg]] * (o2*o2*o2);
    atomicMax(&s_pal[asg], __float_as_uint(av));      // >=0 floats
    atomicMax(&s_pov[asg], __float_as_uint(bestov));
    const int wi = a - w0;
    if ((unsigned)wi < (unsigned)nw) { s_asg[wi] = (unsigned char)asg; s_av[wi] = av; }
  }
  __syncthreads();

  // write phase: dense bbox (memset can't provide gt0 default) + SPARSE
  // fg/cls for claimed window anchors (rest stay at memset zeros).
  if (tid < nw) {
    const int a = w0 + tid;
    const int asg = s_asg[tid];
    const int tgt = (asg != 255) ? asg : 0;   // argmax of all-zero column = 0
    reinterpret_cast<float4*>(out_bbox)[b*AA + a] = s_gb[tgt];
    if (asg != 255) {
      const float norm = s_av[tid] * __uint_as_float(s_pov[asg])
                       / (__uint_as_float(s_pal[asg]) + 1e-9f);
      out_fg[b*AA + a] = 1.f;
      out_cls[(size_t)(b*AA + a)*CC + s_lbl[asg]] = norm;
    }
  }
}

// ---------------------------------------------------------------------------
extern "C" void kernel_launch(void* const* d_in, const int* in_sizes, int n_in,
                              void* d_out, int out_size, void* d_ws, size_t ws_size,
                              hipStream_t stream)
{
  const float* pred_cls  = (const float*)d_in[0];
  const float* pred_bbox = (const float*)d_in[1];
  const float* anchors   = (const float*)d_in[2];
  const int*   gt_cls    = (const int*)  d_in[3];
  const float* gt_bbox   = (const float*)d_in[4];
  const float* mask_gt   = (const float*)d_in[5];

  // ws layout: topkeys u64[B*M*13] @ 0 (53248 B)
  unsigned long long* topkeys = (unsigned long long*)d_ws;

  float* out_cls  = (float*)d_out;
  float* out_bbox = out_cls + (size_t)BB*AA*CC;
  float* out_fg   = out_bbox + (size_t)BB*AA*4;

  // Zero ALL outputs at fill-kernel speed (~6.7 TB/s measured on harness
  // fills). out_cls/out_fg defaults are exactly 0; out_bbox is overwritten
  // densely by k_assign. Runs every call -> deterministic.
  hipMemsetAsync(d_out, 0, (size_t)out_size * sizeof(float), stream);

  k_topk<<<dim3(MM, BB), 512, 0, stream>>>(
      pred_cls, pred_bbox, anchors, gt_cls, gt_bbox, mask_gt, topkeys);
  k_assign<<<dim3(BB*17), 512, 0, stream>>>(
      pred_cls, pred_bbox, anchors, gt_cls, gt_bbox, mask_gt, topkeys,
      out_cls, out_bbox, out_fg);
}

// Round 21
// 47.452 us; speedup vs baseline: 1.1824x; 1.1034x over previous
//
#include <hip/hip_runtime.h>
#include <cstdint>
#include <cstddef>

#define BB 16
#define AA 8400
#define CC 80
#define MM 32
#define TOPK 13
#define NW 8                 // waves (chunks) per row-block
#define CANCH 1056           // anchors per wave-chunk (8*1056 = 8448 >= AA)

// Shared CIoU (clipped) so every use site has the identical formula.
__device__ __forceinline__ float ciou_clip(
    float gx1, float gy1, float gx2, float gy2, float at1,
    float4 pb, float w2, float h2, float at2)
{
  const float w1 = gx2 - gx1, h1 = gy2 - gy1 + 1e-7f;
  const float iw = fmaxf(fminf(gx2, pb.z) - fmaxf(gx1, pb.x), 0.f);
  const float ih = fmaxf(fminf(gy2, pb.w) - fmaxf(gy1, pb.y), 0.f);
  const float inter = iw * ih;
  const float uni = w1*h1 + w2*h2 - inter + 1e-7f;
  const float iou = inter / uni;
  const float cw = fmaxf(gx2, pb.z) - fminf(gx1, pb.x);
  const float ch = fmaxf(gy2, pb.w) - fminf(gy1, pb.y);
  const float c2 = cw*cw + ch*ch + 1e-7f;
  const float rx = pb.x + pb.z - gx1 - gx2;
  const float ry = pb.y + pb.w - gy1 - gy2;
  const float rho2 = (rx*rx + ry*ry) * 0.25f;
  const float dv = at2 - at1;
  const float v = 0.4052847345693511f * dv * dv;
  const float alpha = v / (v - iou + (1.f + 1e-7f));
  return fmaxf(iou - (rho2 / c2 + v * alpha), 0.f);
}

// (val desc, idx asc) as one monotone u64 key; val >= 0 so float bits are
// order-preserving. Sentinel/empty = 0 (loses to every real entry; decodes
// to anchor -1 — ALL decode sites must use unsigned bounds checks).
__device__ __forceinline__ unsigned long long pack_key(float val, int a) {
  return ((unsigned long long)__float_as_uint(val) << 32)
       | (unsigned long long)(0xFFFFFFFFu - (unsigned)a);
}
__device__ __forceinline__ int key_anchor(unsigned long long k) {
  return (int)(0xFFFFFFFFu - (unsigned)(k & 0xFFFFFFFFull));
}

// ---------------------------------------------------------------------------
// K1: per-(b,m) block (8 waves, 512 thr): own mind-test scan -> LDS queue ->
// dense CIoU eval -> per-lane top-13 u64 keys -> per-wave butterfly extract
// -> wave-0 merge of 8x13 -> topkeys[b][m][13]. Masked rows: sentinel keys.
// Zero-tie fill exactness: wave 0 seeds anchors [0,64) with full evals
// (val==0 when out-of-gts; those indices are excluded from the scan);
// a row with <13 positives zero-fills from indices <64 (>=51 zeros there),
// ties resolved by ascending index — matches jax.lax.top_k exactly.
// ---------------------------------------------------------------------------
__global__ __launch_bounds__(512) void k_topk(
    const float* __restrict__ pred_cls, const float* __restrict__ pred_bbox,
    const float* __restrict__ anchors, const int* __restrict__ gt_cls,
    const float* __restrict__ gt_bbox, const float* __restrict__ mask_gt,
    unsigned long long* __restrict__ topkeys)
{
  const int m = blockIdx.x, b = blockIdx.y;
  const int tid = threadIdx.x;
  const int wave = tid >> 6, lane = tid & 63;

  unsigned long long* tk = topkeys + (size_t)(b*MM + m)*TOPK;
  if (mask_gt[b*MM + m] <= 0.f) {        // masked gt: sentinel row
    if (tid < TOPK) tk[tid] = 0ull;
    return;
  }

  __shared__ unsigned short q[NW][CANCH];
  __shared__ unsigned long long s_top[NW][TOPK];

  const float4 gb = reinterpret_cast<const float4*>(gt_bbox)[b*MM + m];
  const float at1 = atanf((gb.z - gb.x) / (gb.w - gb.y + 1e-7f));
  const int lbl = gt_cls[b*MM + m];
  const float*  clsbase = pred_cls + (size_t)b*AA*CC;
  const float4* pbase   = reinterpret_cast<const float4*>(pred_bbox) + (size_t)b*AA;
  const float2* axy     = reinterpret_cast<const float2*>(anchors);

  unsigned long long k13[TOPK];
  #pragma unroll
  for (int i = 0; i < TOPK; ++i) k13[i] = 0ull;

  // wave-0 seed: full eval of anchor a = lane (always a candidate)
  if (wave == 0) {
    const int a = lane;
    const float2 xy = axy[a];
    const float mind = fminf(fminf(xy.x - gb.x, xy.y - gb.y),
                             fminf(gb.z - xy.x, gb.w - xy.y));
    float val = 0.f;
    if (mind > 1e-9f) {
      const float4 pb = pbase[a];
      const float w2 = pb.z - pb.x, h2 = pb.w - pb.y + 1e-7f;
      const float at2 = atanf(w2 / h2);
      const float ov = ciou_clip(gb.x, gb.y, gb.z, gb.w, at1, pb, w2, h2, at2);
      const float o2 = ov * ov;
      val = clsbase[(size_t)a*CC + lbl] * (o2 * o2 * o2);
    }
    k13[0] = pack_key(val, a);
  }

  // mind-test scan -> queue (ascending anchor order)
  const int abase = wave * CANCH;
  int qc = 0;
  for (int s = 0; s < 17; ++s) {
    const int la = s*64 + lane;
    const int a  = abase + la;
    bool pass = false;
    if (la < CANCH && a < AA && !(wave == 0 && a < 64)) {
      const float2 xy = axy[a];
      const float mind = fminf(fminf(xy.x - gb.x, xy.y - gb.y),
                               fminf(gb.z - xy.x, gb.w - xy.y));
      pass = mind > 1e-9f;
    }
    const unsigned long long bal = __ballot(pass);
    if (pass) {
      const int pos = qc + (int)__popcll(bal & ((1ull << lane) - 1ull));
      q[wave][pos] = (unsigned short)la;
    }
    qc += (int)__popcll(bal);
  }

  // dense eval of queue (per-lane stream ascending in a; key compare exact)
  for (int k = lane; k < qc; k += 64) {
    const int a = abase + (int)q[wave][k];
    const float4 pb = pbase[a];
    const float w2 = pb.z - pb.x, h2 = pb.w - pb.y + 1e-7f;
    const float at2 = atanf(w2 / h2);
    const float ov = ciou_clip(gb.x, gb.y, gb.z, gb.w, at1, pb, w2, h2, at2);
    const float o2 = ov * ov;
    const float val = clsbase[(size_t)a*CC + lbl] * (o2 * o2 * o2);
    const unsigned long long key = pack_key(val, a);
    if (key > k13[TOPK-1]) {
      #pragma unroll
      for (int i = TOPK-1; i >= 1; --i)       // static-index shift network
        if (key > k13[i]) k13[i] = (key > k13[i-1]) ? k13[i-1] : key;
      if (key > k13[0]) k13[0] = key;
    }
  }

  // per-wave 13-round extraction (u64 butterfly max) -> LDS
  for (int r = 0; r < TOPK; ++r) {
    unsigned long long bk = k13[0];
    #pragma unroll
    for (int off = 32; off; off >>= 1) {
      const unsigned long long o = __shfl_xor(bk, off);
      if (o > bk) bk = o;
    }
    if (k13[0] == bk) {                       // unique for real keys;
      #pragma unroll                          // sentinel multi-pop harmless
      for (int i = 0; i < TOPK-1; ++i) k13[i] = k13[i+1];
      k13[TOPK-1] = 0ull;
    }
    if (lane == 0) s_top[wave][r] = bk;
  }
  __syncthreads();
  if (wave != 0) return;

  // wave-0 merge of 8x13 = 104 keys (2 static slots/lane) -> topkeys row
  unsigned long long v0 = 0ull, v1 = 0ull;
  {
    const int e0 = lane, e1 = lane + 64;
    v0 = s_top[e0/TOPK][e0%TOPK];
    if (e1 < NW*TOPK) v1 = s_top[e1/TOPK][e1%TOPK];
  }
  for (int r = 0; r < TOPK; ++r) {
    const bool s1 = v1 > v0;
    unsigned long long bk = s1 ? v1 : v0;
    const unsigned long long my = bk;
    #pragma unroll
    for (int off = 32; off; off >>= 1) {
      const unsigned long long o = __shfl_xor(bk, off);
      if (o > bk) bk = o;
    }
    if (lane == 0) tk[r] = bk;
    if (my == bk && bk != 0ull) {             // unique winner pops its slot
      if (s1) v1 = 0ull; else v0 = 0ull;
    }
  }
}

// ---------------------------------------------------------------------------
// K2: 272 blocks (b, 512-anchor window). Build LDS claim bitmap for the
// window from the batch's 416 topkeys (in-gts gate, unsigned sentinel
// guards), then resolve (fg==1 / fg>1 first-max over masked overlaps),
// write anchor_m/al + out_bbox/out_fg densely, atomicMax global pos_*.
// ---------------------------------------------------------------------------
__global__ __launch_bounds__(512) void k_resolve(
    const float* __restrict__ pred_cls, const float* __restrict__ pred_bbox,
    const float* __restrict__ anchors, const int* __restrict__ gt_cls,
    const float* __restrict__ gt_bbox, const float* __restrict__ mask_gt,
    const unsigned long long* __restrict__ topkeys,
    float* __restrict__ out_bbox, float* __restrict__ out_fg,
    int* __restrict__ anchor_m, float* __restrict__ anchor_al,
    unsigned int* __restrict__ pos_align, unsigned int* __restrict__ pos_ovl)
{
  const int b = blockIdx.x / 17, ch = blockIdx.x % 17;
  const int tid = threadIdx.x;
  const int w0 = ch * 512;                  // window [w0, w0+512)
  __shared__ unsigned int s_claim[512];     // window claim bitmap
  __shared__ float4 s_gb[MM];
  __shared__ float s_at[MM], s_mgt[MM];
  __shared__ int s_lbl[MM];

  const float2* axy = reinterpret_cast<const float2*>(anchors);

  if (tid < MM) {
    const float4 g = reinterpret_cast<const float4*>(gt_bbox)[b*MM + tid];
    s_gb[tid] = g;
    s_at[tid] = atanf((g.z - g.x) / (g.w - g.y + 1e-7f));
    s_lbl[tid] = gt_cls[b*MM + tid];
    s_mgt[tid] = mask_gt[b*MM + tid];
  }
  s_claim[tid] = 0u;
  __syncthreads();

  // claim phase: 416 keys -> window bitmap (in-gts gate here)
  if (tid < MM*TOPK) {
    const int m = tid / TOPK;
    const unsigned long long key = topkeys[(size_t)(b*MM + m)*TOPK + tid%TOPK];
    const int a = key_anchor(key);
    if ((unsigned)a < (unsigned)AA && a >= w0 && a < w0 + 512) {
      const float2 xy = axy[a];
      const float4 g = s_gb[m];
      const float mind = fminf(fminf(xy.x - g.x, xy.y - g.y),
                               fminf(g.z - xy.x, g.w - xy.y));
      if (mind > 1e-9f) atomicOr(&s_claim[a - w0], 1u << m);
    }
  }
  __syncthreads();

  const int a = w0 + tid;
  if (a >= AA) return;
  const unsigned cb = s_claim[tid];
  int asg = -1; float av = 0.f;
  if (cb != 0u) {
    const float4 pb = reinterpret_cast<const float4*>(pred_bbox)[b*AA + a];
    const float2 xy = axy[a];
    const float w2 = pb.z - pb.x, h2 = pb.w - pb.y + 1e-7f;
    const float at2 = atanf(w2 / h2);
    float bestov;
    if (__popc(cb) == 1) {
      asg = __ffs(cb) - 1;   // claimed => in-gts && mask_gt>0 already hold
      const float4 g = s_gb[asg];
      bestov = ciou_clip(g.x, g.y, g.z, g.w, s_at[asg], pb, w2, h2, at2);
    } else {
      // is_max: first argmax over ALL m of masked overlaps
      float best = -1.f; int bm = 0;
      for (int m = 0; m < MM; ++m) {
        float ov = 0.f;
        const float4 g = s_gb[m];
        const float mind = fminf(fminf(xy.x - g.x, xy.y - g.y),
                                 fminf(g.z - xy.x, g.w - xy.y));
        if (mind > 1e-9f && s_mgt[m] > 0.f)
          ov = ciou_clip(g.x, g.y, g.z, g.w, s_at[m], pb, w2, h2, at2);
        if (ov > best) { best = ov; bm = m; }   // strict > => first max
      }
      asg = bm; bestov = best;
    }
    const float o2 = bestov * bestov;
    av = pred_cls[(size_t)(b*AA + a)*CC + s_lbl[asg]] * (o2 * o2 * o2);
    atomicMax(&pos_align[b*MM + asg], __float_as_uint(av));    // >=0 floats
    atomicMax(&pos_ovl[b*MM + asg], __float_as_uint(bestov));
  }
  const int tgt = (asg >= 0) ? asg : 0;     // argmax of all-zero column = 0
  reinterpret_cast<float4*>(out_bbox)[b*AA + a] = s_gb[tgt];
  out_fg[b*AA + a] = (asg >= 0) ? 1.f : 0.f;
  anchor_m[b*AA + a] = asg;
  anchor_al[b*AA + a] = av;
}

// ---------------------------------------------------------------------------
// K3: target_cls (B,A,C) float4-coalesced: norm at the label slot, else 0.
// ---------------------------------------------------------------------------
__global__ __launch_bounds__(256) void k_cls(
    const int* __restrict__ anchor_m, const float* __restrict__ anchor_al,
    const unsigned int* __restrict__ pos_align, const unsigned int* __restrict__ pos_ovl,
    const int* __restrict__ gt_cls, float* __restrict__ out_cls)
{
  const int tid = blockIdx.x*256 + threadIdx.x;
  if (tid >= BB*AA*(CC/4)) return;
  const int q  = tid % (CC/4);
  const int ba = tid / (CC/4);
  const int b  = ba / AA;
  const int m  = anchor_m[ba];
  float4 o = make_float4(0.f, 0.f, 0.f, 0.f);
  if (m >= 0) {
    const float pa = __uint_as_float(pos_align[b*MM + m]);
    const float po = __uint_as_float(pos_ovl[b*MM + m]);
    const float norm = anchor_al[ba] * po / (pa + 1e-9f);
    const int lbl = gt_cls[b*MM + m];
    const int c0 = q * 4;
    if (lbl == c0    ) o.x = norm;
    if (lbl == c0 + 1) o.y = norm;
    if (lbl == c0 + 2) o.z = norm;
    if (lbl == c0 + 3) o.w = norm;
  }
  reinterpret_cast<float4*>(out_cls)[tid] = o;
}

// ---------------------------------------------------------------------------
extern "C" void kernel_launch(void* const* d_in, const int* in_sizes, int n_in,
                              void* d_out, int out_size, void* d_ws, size_t ws_size,
                              hipStream_t stream)
{
  const float* pred_cls  = (const float*)d_in[0];
  const float* pred_bbox = (const float*)d_in[1];
  const float* anchors   = (const float*)d_in[2];
  const int*   gt_cls    = (const int*)  d_in[3];
  const float* gt_bbox   = (const float*)d_in[4];
  const float* mask_gt   = (const float*)d_in[5];

  // ws layout:
  //   topkeys    : B*M*13 u64      @ 0        (53248 B)
  //   pos_align  : B*M u32(float)  @ 53248    (2048 B)
  //   pos_ovl    : B*M u32(float)  @ 55296    (2048 B)
  //   anchor_m   : B*A i32         @ 57344    (537600 B)
  //   anchor_al  : B*A f32         @ 594944   (537600 B)
  // total 1132544 B (~1.1 MB)
  char* ws = (char*)d_ws;
  unsigned long long* topkeys = (unsigned long long*)(ws);
  unsigned int* pos_align = (unsigned int*)(ws + 53248);
  unsigned int* pos_ovl   = (unsigned int*)(ws + 55296);
  int*   anchor_m  = (int*)  (ws + 57344);
  float* anchor_al = (float*)(ws + 594944);

  float* out_cls  = (float*)d_out;
  float* out_bbox = out_cls + (size_t)BB*AA*CC;
  float* out_fg   = out_bbox + (size_t)BB*AA*4;

  k_topk<<<dim3(MM, BB), 512, 0, stream>>>(
      pred_cls, pred_bbox, anchors, gt_cls, gt_bbox, mask_gt, topkeys);
  k_resolve<<<dim3(BB*17), 512, 0, stream>>>(
      pred_cls, pred_bbox, anchors, gt_cls, gt_bbox, mask_gt, topkeys,
      out_bbox, out_fg, anchor_m, anchor_al, pos_align, pos_ovl);
  k_cls<<<(BB*AA*(CC/4) + 255)/256, 256, 0, stream>>>(
      anchor_m, anchor_al, pos_align, pos_ovl, gt_cls, out_cls);
}